// Round 1
// baseline (159.407 us; speedup 1.0000x reference)
//
#include <hip/hip_runtime.h>
#include <cmath>

// Tiny transformer block, D=6, S=128, B=8192, fp32.
// One block per batch element; thread s owns sequence row s.
// K/V staged in LDS (rows padded to 8 floats); softmax is single-pass
// without max-subtraction (scores ~N(0,0.6^2), fp32 exp safe).

constexpr int D = 6;
constexpr int S = 128;
#define EPS 1e-5f
#define RSQRT_D 0.4082482904638631f   // 1/sqrt(6)
#define RSQRT_2 0.7071067811865475f   // 1/sqrt(2)

__global__ __launch_bounds__(S, 4) void txblock_kernel(
    const float* __restrict__ x,
    const float* __restrict__ ln1_w, const float* __restrict__ ln1_b,
    const float* __restrict__ wqkv,  const float* __restrict__ bqkv,
    const float* __restrict__ wo,    const float* __restrict__ bo,
    const float* __restrict__ ln2_w, const float* __restrict__ ln2_b,
    const float* __restrict__ w1,    const float* __restrict__ b1,
    const float* __restrict__ w2,    const float* __restrict__ b2,
    float* __restrict__ out)
{
    __shared__ float sK[S][8];   // padded: row base 32B-aligned -> b128+b64 reads
    __shared__ float sV[S][8];

    const int b = blockIdx.x;
    const int s = threadIdx.x;
    const float* xrow = x + ((size_t)b * S + s) * D;
    float*      orow = out + ((size_t)b * S + s) * D;

    // ---- load x row ----
    float xv[D];
    #pragma unroll
    for (int d = 0; d < D; ++d) xv[d] = xrow[d];

    // ---- ln1 ----
    float m = 0.f;
    #pragma unroll
    for (int d = 0; d < D; ++d) m += xv[d];
    m *= (1.0f / D);
    float var = 0.f;
    #pragma unroll
    for (int d = 0; d < D; ++d) { float t = xv[d] - m; var += t * t; }
    var *= (1.0f / D);
    float rstd = rsqrtf(var + EPS);
    float h[D];
    #pragma unroll
    for (int d = 0; d < D; ++d)
        h[d] = (xv[d] - m) * rstd * ln1_w[d] + ln1_b[d];

    // ---- qkv projection (weights are wave-uniform -> scalar-cached) ----
    float q[D], kk[D], vv[D];
    #pragma unroll
    for (int j = 0; j < D; ++j) {
        float aq = bqkv[j], ak = bqkv[D + j], av = bqkv[2 * D + j];
        #pragma unroll
        for (int d = 0; d < D; ++d) {
            const float* wrow = wqkv + d * 3 * D;
            aq += h[d] * wrow[j];
            ak += h[d] * wrow[D + j];
            av += h[d] * wrow[2 * D + j];
        }
        q[j]  = aq * RSQRT_D;   // fold 1/sqrt(D) into q
        kk[j] = ak;
        vv[j] = av;
    }

    #pragma unroll
    for (int d = 0; d < D; ++d) { sK[s][d] = kk[d]; sV[s][d] = vv[d]; }
    __syncthreads();

    // ---- causal attention, single-pass softmax (no max subtraction) ----
    float l = 0.f;
    float acc[D] = {0.f, 0.f, 0.f, 0.f, 0.f, 0.f};
    for (int j = 0; j <= s; ++j) {
        float dot = q[0] * sK[j][0] + q[1] * sK[j][1] + q[2] * sK[j][2]
                  + q[3] * sK[j][3] + q[4] * sK[j][4] + q[5] * sK[j][5];
        float p = __expf(dot);
        l += p;
        #pragma unroll
        for (int d = 0; d < D; ++d) acc[d] += p * sV[j][d];
    }
    float invl = 1.0f / l;
    float av6[D];
    #pragma unroll
    for (int d = 0; d < D; ++d) av6[d] = acc[d] * invl;

    // ---- o = (attn@v)@wo + bo ; residual ----
    float x2[D];
    #pragma unroll
    for (int d = 0; d < D; ++d) {
        float o = bo[d];
        #pragma unroll
        for (int e = 0; e < D; ++e) o += av6[e] * wo[e * D + d];
        x2[d] = xv[d] + o;
    }

    // ---- ln2 ----
    float m2 = 0.f;
    #pragma unroll
    for (int d = 0; d < D; ++d) m2 += x2[d];
    m2 *= (1.0f / D);
    float var2 = 0.f;
    #pragma unroll
    for (int d = 0; d < D; ++d) { float t = x2[d] - m2; var2 += t * t; }
    var2 *= (1.0f / D);
    float rstd2 = rsqrtf(var2 + EPS);
    float h2[D];
    #pragma unroll
    for (int d = 0; d < D; ++d)
        h2[d] = (x2[d] - m2) * rstd2 * ln2_w[d] + ln2_b[d];

    // ---- FFN: gelu(h2@w1+b1)@w2+b2 ; residual ----
    float g[D];
    #pragma unroll
    for (int j = 0; j < D; ++j) {
        float a = b1[j];
        #pragma unroll
        for (int d = 0; d < D; ++d) a += h2[d] * w1[d * D + j];
        g[j] = 0.5f * a * (1.0f + erff(a * RSQRT_2));  // exact gelu
    }
    #pragma unroll
    for (int d = 0; d < D; ++d) {
        float a = b2[d];
        #pragma unroll
        for (int e = 0; e < D; ++e) a += g[e] * w2[e * D + d];
        orow[d] = x2[d] + a;
    }
}

extern "C" void kernel_launch(void* const* d_in, const int* in_sizes, int n_in,
                              void* d_out, int out_size, void* d_ws, size_t ws_size,
                              hipStream_t stream) {
    const float* x     = (const float*)d_in[0];
    const float* ln1_w = (const float*)d_in[1];
    const float* ln1_b = (const float*)d_in[2];
    const float* wqkv  = (const float*)d_in[3];
    const float* bqkv  = (const float*)d_in[4];
    const float* wo    = (const float*)d_in[5];
    const float* bo    = (const float*)d_in[6];
    const float* ln2_w = (const float*)d_in[7];
    const float* ln2_b = (const float*)d_in[8];
    const float* w1    = (const float*)d_in[9];
    const float* b1    = (const float*)d_in[10];
    const float* w2    = (const float*)d_in[11];
    const float* b2    = (const float*)d_in[12];
    float* out = (float*)d_out;

    const int B = in_sizes[0] / (S * D);
    txblock_kernel<<<B, S, 0, stream>>>(x, ln1_w, ln1_b, wqkv, bqkv, wo, bo,
                                        ln2_w, ln2_b, w1, b1, w2, b2, out);
}

// Round 2
// 147.774 us; speedup vs baseline: 1.0787x; 1.0787x over previous
//
#include <hip/hip_runtime.h>
#include <cmath>

// Tiny transformer block, D=6, S=128, B=8192, fp32.
// One block per batch element; thread s owns sequence row s.
// R2: packed-fp32 (v_pk_fma) attention inner loop, exp2-folded softmax,
// uniform loop bounds + predication, stride-20 interleaved KV rows,
// exp2-based tanh-GELU.

typedef float v2f __attribute__((ext_vector_type(2)));

constexpr int D = 6;
constexpr int S = 128;
#define EPS 1e-5f
#define RSQRT_D 0.4082482904638631f   // 1/sqrt(6)
#define LOG2E   1.4426950408889634f

#if __has_builtin(__builtin_amdgcn_exp2f)
#define EXP2F(x) __builtin_amdgcn_exp2f(x)
#else
#define EXP2F(x) exp2f(x)
#endif

#if __has_builtin(__builtin_amdgcn_rcpf)
#define RCPF(x) __builtin_amdgcn_rcpf(x)
#else
#define RCPF(x) (1.0f / (x))
#endif

#define PKFMA(a, b, c) __builtin_elementwise_fma((a), (b), (c))

__global__ __launch_bounds__(S, 8) void txblock_kernel(
    const float* __restrict__ x,
    const float* __restrict__ ln1_w, const float* __restrict__ ln1_b,
    const float* __restrict__ wqkv,  const float* __restrict__ bqkv,
    const float* __restrict__ wo,    const float* __restrict__ bo,
    const float* __restrict__ ln2_w, const float* __restrict__ ln2_b,
    const float* __restrict__ w1,    const float* __restrict__ b1,
    const float* __restrict__ w2,    const float* __restrict__ b2,
    float* __restrict__ out)
{
    // Row r: [k01,k23,k45, v01,v23,v45, pad x4] -> 20 floats (80 B) stride.
    // 16B-aligned row base => 3x ds_read_b128 broadcast per iteration.
    // Stride 20 floats: write aliasing 8-way (vs 16-way at stride 8).
    __shared__ v2f kv[S][10];

    const int b = blockIdx.x;
    const int s = threadIdx.x;
    const float* xrow = x + ((size_t)b * S + s) * D;
    float*      orow = out + ((size_t)b * S + s) * D;

    // ---- load x row (8B-aligned: row offset = 24B * idx) ----
    v2f xv01 = ((const v2f*)xrow)[0];
    v2f xv23 = ((const v2f*)xrow)[1];
    v2f xv45 = ((const v2f*)xrow)[2];
    float xv[D] = {xv01[0], xv01[1], xv23[0], xv23[1], xv45[0], xv45[1]};

    // ---- ln1 ----
    float m = 0.f;
    #pragma unroll
    for (int d = 0; d < D; ++d) m += xv[d];
    m *= (1.0f / D);
    float var = 0.f;
    #pragma unroll
    for (int d = 0; d < D; ++d) { float t = xv[d] - m; var += t * t; }
    var *= (1.0f / D);
    float rstd = rsqrtf(var + EPS);
    float h[D];
    #pragma unroll
    for (int d = 0; d < D; ++d)
        h[d] = (xv[d] - m) * rstd * ln1_w[d] + ln1_b[d];

    // ---- qkv projection (weights wave-uniform -> scalar regs) ----
    float q[D], kk[D], vv[D];
    #pragma unroll
    for (int j = 0; j < D; ++j) {
        float aq = bqkv[j], ak = bqkv[D + j], av = bqkv[2 * D + j];
        #pragma unroll
        for (int d = 0; d < D; ++d) {
            const float* wrow = wqkv + d * 3 * D;
            aq += h[d] * wrow[j];
            ak += h[d] * wrow[D + j];
            av += h[d] * wrow[2 * D + j];
        }
        q[j]  = aq * (RSQRT_D * LOG2E);  // fold 1/sqrt(D) and log2(e) into q
        kk[j] = ak;
        vv[j] = av;
    }

    kv[s][0] = (v2f){kk[0], kk[1]};
    kv[s][1] = (v2f){kk[2], kk[3]};
    kv[s][2] = (v2f){kk[4], kk[5]};
    kv[s][3] = (v2f){vv[0], vv[1]};
    kv[s][4] = (v2f){vv[2], vv[3]};
    kv[s][5] = (v2f){vv[4], vv[5]};
    __syncthreads();

    // ---- causal attention, single-pass softmax (exp2 domain) ----
    // Uniform per-wave trip count (64 for wave0, 128 for wave1); masked
    // lanes get score -100 -> p ~ 8e-31, negligible in l and acc.
    const int jend = __builtin_amdgcn_readfirstlane((s & 64) ? S : 64);

    v2f q01 = {q[0], q[1]}, q23 = {q[2], q[3]}, q45 = {q[4], q[5]};
    v2f acc01 = {0.f, 0.f}, acc23 = {0.f, 0.f}, acc45 = {0.f, 0.f};
    float l = 0.f;

    const v2f* __restrict__ rowp = &kv[0][0];
    for (int j0 = 0; j0 < jend; j0 += 4) {
        #pragma unroll
        for (int u = 0; u < 4; ++u) {
            const int j = j0 + u;
            const v2f* r = rowp + j * 10;
            v2f k01 = r[0], k23 = r[1], k45 = r[2];
            v2f d2 = PKFMA(q01, k01, PKFMA(q23, k23, q45 * k45));
            float dot = d2[0] + d2[1];
            float sel = (j <= s) ? dot : -100.0f;
            float p = EXP2F(sel);
            l += p;
            v2f pv = {p, p};
            v2f v01 = r[3], v23 = r[4], v45 = r[5];
            acc01 = PKFMA(pv, v01, acc01);
            acc23 = PKFMA(pv, v23, acc23);
            acc45 = PKFMA(pv, v45, acc45);
        }
    }

    float invl = 1.0f / l;
    float av6[D] = {acc01[0] * invl, acc01[1] * invl, acc23[0] * invl,
                    acc23[1] * invl, acc45[0] * invl, acc45[1] * invl};

    // ---- o = (attn@v)@wo + bo ; residual ----
    float x2[D];
    #pragma unroll
    for (int d = 0; d < D; ++d) {
        float o = bo[d];
        #pragma unroll
        for (int e = 0; e < D; ++e) o += av6[e] * wo[e * D + d];
        x2[d] = xv[d] + o;
    }

    // ---- ln2 ----
    float m2 = 0.f;
    #pragma unroll
    for (int d = 0; d < D; ++d) m2 += x2[d];
    m2 *= (1.0f / D);
    float var2 = 0.f;
    #pragma unroll
    for (int d = 0; d < D; ++d) { float t = x2[d] - m2; var2 += t * t; }
    var2 *= (1.0f / D);
    float rstd2 = rsqrtf(var2 + EPS);
    float h2[D];
    #pragma unroll
    for (int d = 0; d < D; ++d)
        h2[d] = (x2[d] - m2) * rstd2 * ln2_w[d] + ln2_b[d];

    // ---- FFN: gelu(h2@w1+b1)@w2+b2 ; residual ----
    // tanh-GELU: gelu(a) ~= a * sigmoid(1.5957691216*(a + 0.044715 a^3))
    //          = a / (1 + exp2(-2.3022229*(a + 0.044715 a^3)))
    // max abs error ~3e-4, way under the 0.1 threshold.
    float g[D];
    #pragma unroll
    for (int j = 0; j < D; ++j) {
        float a = b1[j];
        #pragma unroll
        for (int d = 0; d < D; ++d) a += h2[d] * w1[d * D + j];
        float t  = a * a;
        float in = fmaf(0.044715f * t, a, a);
        float e  = EXP2F(in * -2.3022229f);
        float r  = RCPF(1.0f + e);
        g[j] = a * r;
    }
    v2f o01, o23, o45;
    float og[D];
    #pragma unroll
    for (int d = 0; d < D; ++d) {
        float a = b2[d];
        #pragma unroll
        for (int e = 0; e < D; ++e) a += g[e] * w2[e * D + d];
        og[d] = x2[d] + a;
    }
    o01 = (v2f){og[0], og[1]};
    o23 = (v2f){og[2], og[3]};
    o45 = (v2f){og[4], og[5]};
    ((v2f*)orow)[0] = o01;
    ((v2f*)orow)[1] = o23;
    ((v2f*)orow)[2] = o45;
}

extern "C" void kernel_launch(void* const* d_in, const int* in_sizes, int n_in,
                              void* d_out, int out_size, void* d_ws, size_t ws_size,
                              hipStream_t stream) {
    const float* x     = (const float*)d_in[0];
    const float* ln1_w = (const float*)d_in[1];
    const float* ln1_b = (const float*)d_in[2];
    const float* wqkv  = (const float*)d_in[3];
    const float* bqkv  = (const float*)d_in[4];
    const float* wo    = (const float*)d_in[5];
    const float* bo    = (const float*)d_in[6];
    const float* ln2_w = (const float*)d_in[7];
    const float* ln2_b = (const float*)d_in[8];
    const float* w1    = (const float*)d_in[9];
    const float* b1    = (const float*)d_in[10];
    const float* w2    = (const float*)d_in[11];
    const float* b2    = (const float*)d_in[12];
    float* out = (float*)d_out;

    const int B = in_sizes[0] / (S * D);
    txblock_kernel<<<B, S, 0, stream>>>(x, ln1_w, ln1_b, wqkv, bqkv, wo, bo,
                                        ln2_w, ln2_b, w1, b1, w2, b2, out);
}

// Round 3
// 122.304 us; speedup vs baseline: 1.3034x; 1.2083x over previous
//
#include <hip/hip_runtime.h>
#include <cmath>

// Tiny transformer block, D=6, S=128, B=8192, fp32.
// R3: MFMA flash attention. Block = 1 batch (128 threads, 2 waves).
//  - Q,K staged in LDS as bf16 rows of 16 (features 6..15 zero).
//  - V^T staged in LDS with a ones-row at n=6 -> PV MFMA also yields l.
//  - S^T = K@Q^T via mfma_f32_32x32x16_bf16 (1 MFMA per 32x32 tile),
//    exp2 softmax (scale*log2e folded into q), causal mask on diag tiles,
//    P repacked to A-layout via v_perm + lane^32 bpermute + cndmask,
//    O += P@[V|1] via 2 MFMAs.
//  - Waves take m-tiles {0,3} / {1,2}: 5 causal tiles each (balanced).
// Scalar epilogue (wo, LN2, FFN) identical to R2 (known good).

typedef float v2f  __attribute__((ext_vector_type(2)));
typedef short s8v  __attribute__((ext_vector_type(8)));   // 8 bf16 = 4 VGPRs
typedef float f16v __attribute__((ext_vector_type(16)));  // MFMA accum

constexpr int D = 6;
constexpr int S = 128;
#define EPS 1e-5f
#define RSQRT_D 0.4082482904638631f   // 1/sqrt(6)
#define LOG2E   1.4426950408889634f

#define EXP2F(x) __builtin_amdgcn_exp2f(x)
#define RCPF(x)  __builtin_amdgcn_rcpf(x)

union U4 { uint32_t u[4]; s8v v; };

// pack two f32 -> (trunc_bf16(hi)<<16) | trunc_bf16(lo), one v_perm_b32
__device__ __forceinline__ uint32_t pkbf(float hi, float lo) {
    return __builtin_amdgcn_perm(__builtin_bit_cast(uint32_t, hi),
                                 __builtin_bit_cast(uint32_t, lo),
                                 0x07060302u);
}
__device__ __forceinline__ uint16_t bf16t(float x) {
    return (uint16_t)(__builtin_bit_cast(uint32_t, x) >> 16);
}

__global__ __launch_bounds__(S, 3) void txblock_kernel(
    const float* __restrict__ x,
    const float* __restrict__ ln1_w, const float* __restrict__ ln1_b,
    const float* __restrict__ wqkv,  const float* __restrict__ bqkv,
    const float* __restrict__ wo,    const float* __restrict__ bo,
    const float* __restrict__ ln2_w, const float* __restrict__ ln2_b,
    const float* __restrict__ w1,    const float* __restrict__ b1,
    const float* __restrict__ w2,    const float* __restrict__ b2,
    float* __restrict__ out)
{
    __shared__ uint32_t qlds[S][8];   // bf16 rows of 16 (pairs packed)
    __shared__ uint32_t klds[S][8];
    __shared__ uint16_t vt[8][S];     // V^T rows d=0..5; row6=1.0; row7=0
    __shared__ float    obuf[S][8];   // o[0..5], l at [6]

    const int b = blockIdx.x;
    const int s = threadIdx.x;
    const float* xrow = x + ((size_t)b * S + s) * D;
    float*      orow = out + ((size_t)b * S + s) * D;

    // ---- load x row ----
    v2f xv01 = ((const v2f*)xrow)[0];
    v2f xv23 = ((const v2f*)xrow)[1];
    v2f xv45 = ((const v2f*)xrow)[2];
    float xv[D] = {xv01[0], xv01[1], xv23[0], xv23[1], xv45[0], xv45[1]};

    // ---- ln1 ----
    float m = 0.f;
    #pragma unroll
    for (int d = 0; d < D; ++d) m += xv[d];
    m *= (1.0f / D);
    float var = 0.f;
    #pragma unroll
    for (int d = 0; d < D; ++d) { float t = xv[d] - m; var += t * t; }
    var *= (1.0f / D);
    float rstd = rsqrtf(var + EPS);
    float h1[D];
    #pragma unroll
    for (int d = 0; d < D; ++d)
        h1[d] = (xv[d] - m) * rstd * ln1_w[d] + ln1_b[d];

    // ---- qkv projection (weights wave-uniform -> scalar regs) ----
    float q[D], kk[D], vv[D];
    #pragma unroll
    for (int j = 0; j < D; ++j) {
        float aq = bqkv[j], ak = bqkv[D + j], av = bqkv[2 * D + j];
        #pragma unroll
        for (int d = 0; d < D; ++d) {
            const float* wrow = wqkv + d * 3 * D;
            aq += h1[d] * wrow[j];
            ak += h1[d] * wrow[D + j];
            av += h1[d] * wrow[2 * D + j];
        }
        q[j]  = aq * (RSQRT_D * LOG2E);  // fold 1/sqrt(D), log2(e) into q
        kk[j] = ak;
        vv[j] = av;
    }

    // ---- stage Q, K (bf16 rows of 16), V^T (+ones row) ----
    qlds[s][0] = pkbf(q[1], q[0]);
    qlds[s][1] = pkbf(q[3], q[2]);
    qlds[s][2] = pkbf(q[5], q[4]);
    qlds[s][3] = 0; qlds[s][4] = 0; qlds[s][5] = 0; qlds[s][6] = 0; qlds[s][7] = 0;
    klds[s][0] = pkbf(kk[1], kk[0]);
    klds[s][1] = pkbf(kk[3], kk[2]);
    klds[s][2] = pkbf(kk[5], kk[4]);
    klds[s][3] = 0; klds[s][4] = 0; klds[s][5] = 0; klds[s][6] = 0; klds[s][7] = 0;
    #pragma unroll
    for (int d = 0; d < D; ++d) vt[d][s] = bf16t(vv[d]);
    vt[6][s] = 0x3F80;  // bf16 1.0 -> l column
    vt[7][s] = 0;
    __syncthreads();

    // ---- MFMA flash attention ----
    const int wv = s >> 6;          // wave id 0/1
    const int ln = s & 31;          // lane%32: q column (C), m/n row (A/B)
    const int hw = (s >> 5) & 1;    // half-wave: k-block selector
    const int ne = (ln < 6) ? ln : 6;  // V^T row (clamped -> ones row)

    const int mt0 = wv ? 1 : 0;
    const int mt1 = wv ? 2 : 3;

    #pragma unroll
    for (int pass = 0; pass < 2; ++pass) {
        const int mt = pass ? mt1 : mt0;
        U4 qf; qf.v = *(const s8v*)&qlds[mt * 32 + ln][hw * 4];
        f16v O = (f16v)(0.0f);
        for (int kt = 0; kt <= mt; ++kt) {
            s8v kf = *(const s8v*)&klds[kt * 32 + ln][hw * 4];
            // S^T tile: C1[j][q] ; C layout: col=lane&31=q, row=(r&3)+8*(r>>2)+4*hw=j
            f16v c1 = __builtin_amdgcn_mfma_f32_32x32x16_bf16(
                          kf, qf.v, (f16v)(0.0f), 0, 0, 0);
            float p[16];
            #pragma unroll
            for (int r = 0; r < 16; ++r) p[r] = EXP2F(c1[r]);
            if (kt == mt) {  // diagonal tile: causal mask (wave-uniform branch)
                #pragma unroll
                for (int r = 0; r < 16; ++r) {
                    int jl = (r & 3) + 8 * (r >> 2) + 4 * hw;
                    p[r] = (jl > ln) ? 0.0f : p[r];
                }
            }
            // pack p -> bf16 pairs (j adjacent), exchange with lane^32,
            // assemble A-layout fragments for P (m=q=lane&31, k=j)
            uint32_t pk[8], rp[8];
            #pragma unroll
            for (int t = 0; t < 8; ++t) pk[t] = pkbf(p[2 * t + 1], p[2 * t]);
            #pragma unroll
            for (int t = 0; t < 8; ++t)
                rp[t] = (uint32_t)__shfl_xor((int)pk[t], 32);
            U4 a1, a2;
            a1.u[0] = hw ? rp[2] : pk[0];
            a1.u[1] = hw ? rp[3] : pk[1];
            a1.u[2] = hw ? pk[2] : rp[0];
            a1.u[3] = hw ? pk[3] : rp[1];
            a2.u[0] = hw ? rp[6] : pk[4];
            a2.u[1] = hw ? rp[7] : pk[5];
            a2.u[2] = hw ? pk[6] : rp[4];
            a2.u[3] = hw ? pk[7] : rp[5];
            // B = [V|1]: B[k=j][n=d], n=lane&31 clamped to ones row
            s8v b1 = *(const s8v*)&vt[ne][kt * 32 + hw * 8];
            s8v b2 = *(const s8v*)&vt[ne][kt * 32 + 16 + hw * 8];
            O = __builtin_amdgcn_mfma_f32_32x32x16_bf16(a1.v, b1, O, 0, 0, 0);
            O = __builtin_amdgcn_mfma_f32_32x32x16_bf16(a2.v, b2, O, 0, 0, 0);
        }
        // O C-layout: col=lane&31=d (0..5; >=6 all hold l), row=q
        if (ln < 7) {
            #pragma unroll
            for (int r = 0; r < 16; ++r) {
                int row = (r & 3) + 8 * (r >> 2) + 4 * hw;
                obuf[mt * 32 + row][ln] = O[r];
            }
        }
    }
    __syncthreads();

    // ---- epilogue (per-thread, as R2) ----
    float invl = RCPF(obuf[s][6]);
    float av6[D];
    #pragma unroll
    for (int d = 0; d < D; ++d) av6[d] = obuf[s][d] * invl;

    float x2[D];
    #pragma unroll
    for (int d = 0; d < D; ++d) {
        float o = bo[d];
        #pragma unroll
        for (int e = 0; e < D; ++e) o += av6[e] * wo[e * D + d];
        x2[d] = xv[d] + o;
    }

    float m2 = 0.f;
    #pragma unroll
    for (int d = 0; d < D; ++d) m2 += x2[d];
    m2 *= (1.0f / D);
    float var2 = 0.f;
    #pragma unroll
    for (int d = 0; d < D; ++d) { float t = x2[d] - m2; var2 += t * t; }
    var2 *= (1.0f / D);
    float rstd2 = rsqrtf(var2 + EPS);
    float h2[D];
    #pragma unroll
    for (int d = 0; d < D; ++d)
        h2[d] = (x2[d] - m2) * rstd2 * ln2_w[d] + ln2_b[d];

    // tanh-GELU via exp2 (max abs err ~3e-4)
    float g[D];
    #pragma unroll
    for (int j = 0; j < D; ++j) {
        float a = b1[j];
        #pragma unroll
        for (int d = 0; d < D; ++d) a += h2[d] * w1[d * D + j];
        float t  = a * a;
        float in = fmaf(0.044715f * t, a, a);
        float e  = EXP2F(in * -2.3022229f);
        float r  = RCPF(1.0f + e);
        g[j] = a * r;
    }
    float og[D];
    #pragma unroll
    for (int d = 0; d < D; ++d) {
        float a = b2[d];
        #pragma unroll
        for (int e = 0; e < D; ++e) a += g[e] * w2[e * D + d];
        og[d] = x2[d] + a;
    }
    ((v2f*)orow)[0] = (v2f){og[0], og[1]};
    ((v2f*)orow)[1] = (v2f){og[2], og[3]};
    ((v2f*)orow)[2] = (v2f){og[4], og[5]};
}

extern "C" void kernel_launch(void* const* d_in, const int* in_sizes, int n_in,
                              void* d_out, int out_size, void* d_ws, size_t ws_size,
                              hipStream_t stream) {
    const float* x     = (const float*)d_in[0];
    const float* ln1_w = (const float*)d_in[1];
    const float* ln1_b = (const float*)d_in[2];
    const float* wqkv  = (const float*)d_in[3];
    const float* bqkv  = (const float*)d_in[4];
    const float* wo    = (const float*)d_in[5];
    const float* bo    = (const float*)d_in[6];
    const float* ln2_w = (const float*)d_in[7];
    const float* ln2_b = (const float*)d_in[8];
    const float* w1    = (const float*)d_in[9];
    const float* b1    = (const float*)d_in[10];
    const float* w2    = (const float*)d_in[11];
    const float* b2    = (const float*)d_in[12];
    float* out = (float*)d_out;

    const int B = in_sizes[0] / (S * D);
    txblock_kernel<<<B, S, 0, stream>>>(x, ln1_w, ln1_b, wqkv, bqkv, wo, bo,
                                        ln2_w, ln2_b, w1, b1, w2, b2, out);
}

// Round 4
// 118.634 us; speedup vs baseline: 1.3437x; 1.0309x over previous
//
#include <hip/hip_runtime.h>
#include <cmath>

// Tiny transformer block, D=6, S=128, B=8192, fp32.
// R4: R3's verified MFMA flash-attention core, plus:
//  - conflict-free LDS geometry: q/k rows 40B stride (2-way = free, b64 frag
//    loads), vt rows 136 cols, obuf rows 10 floats.
//  - __launch_bounds__(128,4) for occupancy (17.5KB LDS -> 8 blocks/CU OK).
//  - packed v_pk_fma_f32 in qkv projection and wo/FFN epilogue.
//  - chunked exp->pack->shfl to bound register pressure.

typedef float    v2f  __attribute__((ext_vector_type(2)));
typedef uint32_t u2   __attribute__((ext_vector_type(2)));
typedef short    s8v  __attribute__((ext_vector_type(8)));   // 8 bf16
typedef float    f16v __attribute__((ext_vector_type(16)));  // MFMA accum

constexpr int D = 6;
constexpr int S = 128;
#define EPS 1e-5f
#define RSQRT_D 0.4082482904638631f   // 1/sqrt(6)
#define LOG2E   1.4426950408889634f

#define EXP2F(x) __builtin_amdgcn_exp2f(x)
#define RCPF(x)  __builtin_amdgcn_rcpf(x)
#define PKFMA(a, b, c) __builtin_elementwise_fma((a), (b), (c))

union U4 { uint32_t u[4]; u2 h[2]; s8v v; };

// pack two f32 -> (trunc_bf16(hi)<<16) | trunc_bf16(lo), one v_perm_b32
__device__ __forceinline__ uint32_t pkbf(float hi, float lo) {
    return __builtin_amdgcn_perm(__builtin_bit_cast(uint32_t, hi),
                                 __builtin_bit_cast(uint32_t, lo),
                                 0x07060302u);
}
__device__ __forceinline__ uint16_t bf16t(float x) {
    return (uint16_t)(__builtin_bit_cast(uint32_t, x) >> 16);
}

__global__ __launch_bounds__(S, 4) void txblock_kernel(
    const float* __restrict__ x,
    const float* __restrict__ ln1_w, const float* __restrict__ ln1_b,
    const float* __restrict__ wqkv,  const float* __restrict__ bqkv,
    const float* __restrict__ wo,    const float* __restrict__ bo,
    const float* __restrict__ ln2_w, const float* __restrict__ ln2_b,
    const float* __restrict__ w1,    const float* __restrict__ b1,
    const float* __restrict__ w2,    const float* __restrict__ b2,
    float* __restrict__ out)
{
    // Row stride 10 dwords (40B): gcd(10,32)=2 -> 2-way bank aliasing = free
    // for both the staging stores and the per-row fragment reads (2x b64).
    __shared__ uint32_t qlds[S][10];  // bf16 pairs, dwords 0..7 = features 0..15
    __shared__ uint32_t klds[S][10];
    __shared__ uint16_t vt[8][S + 8]; // V^T rows d=0..5; row6=1.0; row7=0; 272B stride
    __shared__ float    obuf[S][10];  // o[0..5], l at [6]; 40B stride

    const int b = blockIdx.x;
    const int s = threadIdx.x;
    const float* xrow = x + ((size_t)b * S + s) * D;
    float*      orow = out + ((size_t)b * S + s) * D;

    // ---- load x row (8B-aligned) ----
    v2f xv01 = ((const v2f*)xrow)[0];
    v2f xv23 = ((const v2f*)xrow)[1];
    v2f xv45 = ((const v2f*)xrow)[2];
    float xv[D] = {xv01[0], xv01[1], xv23[0], xv23[1], xv45[0], xv45[1]};

    // ---- ln1 ----
    float m = 0.f;
    #pragma unroll
    for (int d = 0; d < D; ++d) m += xv[d];
    m *= (1.0f / D);
    float var = 0.f;
    #pragma unroll
    for (int d = 0; d < D; ++d) { float t = xv[d] - m; var += t * t; }
    var *= (1.0f / D);
    float rstd = rsqrtf(var + EPS);
    float h1[D];
    #pragma unroll
    for (int d = 0; d < D; ++d)
        h1[d] = (xv[d] - m) * rstd * ln1_w[d] + ln1_b[d];

    // ---- qkv projection, packed pairs over output column j ----
    v2f aq[3], ak[3], av[3];
    #pragma unroll
    for (int jp = 0; jp < 3; ++jp) {
        aq[jp] = ((const v2f*)bqkv)[jp];
        ak[jp] = ((const v2f*)(bqkv + D))[jp];
        av[jp] = ((const v2f*)(bqkv + 2 * D))[jp];
    }
    #pragma unroll
    for (int d = 0; d < D; ++d) {
        const float* wrow = wqkv + d * 3 * D;
        v2f hd = {h1[d], h1[d]};
        #pragma unroll
        for (int jp = 0; jp < 3; ++jp) {
            aq[jp] = PKFMA(hd, ((const v2f*)wrow)[jp], aq[jp]);
            ak[jp] = PKFMA(hd, ((const v2f*)(wrow + D))[jp], ak[jp]);
            av[jp] = PKFMA(hd, ((const v2f*)(wrow + 2 * D))[jp], av[jp]);
        }
    }
    const v2f qscale = {RSQRT_D * LOG2E, RSQRT_D * LOG2E};

    // ---- stage Q, K (bf16 rows of 16; features 6..15 zero), V^T (+ones) ----
    #pragma unroll
    for (int jp = 0; jp < 3; ++jp) {
        v2f qs = aq[jp] * qscale;
        qlds[s][jp] = pkbf(qs[1], qs[0]);
        klds[s][jp] = pkbf(ak[jp][1], ak[jp][0]);
    }
    #pragma unroll
    for (int c = 3; c < 8; ++c) { qlds[s][c] = 0; klds[s][c] = 0; }
    vt[0][s] = bf16t(av[0][0]);
    vt[1][s] = bf16t(av[0][1]);
    vt[2][s] = bf16t(av[1][0]);
    vt[3][s] = bf16t(av[1][1]);
    vt[4][s] = bf16t(av[2][0]);
    vt[5][s] = bf16t(av[2][1]);
    vt[6][s] = 0x3F80;  // bf16 1.0 -> l column
    vt[7][s] = 0;
    __syncthreads();

    // ---- MFMA flash attention (core identical to R3, verified) ----
    const int wv = s >> 6;           // wave id 0/1
    const int ln = s & 31;           // lane%32
    const int hw = (s >> 5) & 1;     // half-wave: k-block selector
    const int ne = (ln < 6) ? ln : 6;

    const int mt0 = wv ? 1 : 0;
    const int mt1 = wv ? 2 : 3;

    #pragma unroll
    for (int pass = 0; pass < 2; ++pass) {
        const int mt = pass ? mt1 : mt0;
        U4 qf;
        {
            const u2* p = (const u2*)&qlds[mt * 32 + ln][hw * 4];
            qf.h[0] = p[0]; qf.h[1] = p[1];
        }
        f16v O = (f16v)(0.0f);
        for (int kt = 0; kt <= mt; ++kt) {
            U4 kf;
            {
                const u2* p = (const u2*)&klds[kt * 32 + ln][hw * 4];
                kf.h[0] = p[0]; kf.h[1] = p[1];
            }
            // S^T tile: C[j][q]; col=lane&31=q, row=(r&3)+8*(r>>2)+4*hw=j
            f16v c1 = __builtin_amdgcn_mfma_f32_32x32x16_bf16(
                          kf.v, qf.v, (f16v)(0.0f), 0, 0, 0);
            uint32_t pk[8], rp[8];
            #pragma unroll
            for (int t = 0; t < 8; ++t) {
                float p0 = EXP2F(c1[2 * t]);
                float p1 = EXP2F(c1[2 * t + 1]);
                if (kt == mt) {  // diagonal tile: causal mask (wave-uniform)
                    const int j0 = ((2 * t) & 3) + 8 * ((2 * t) >> 2) + 4 * hw;
                    const int j1 = ((2 * t + 1) & 3) + 8 * ((2 * t + 1) >> 2) + 4 * hw;
                    p0 = (j0 > ln) ? 0.0f : p0;
                    p1 = (j1 > ln) ? 0.0f : p1;
                }
                pk[t] = pkbf(p1, p0);
                rp[t] = (uint32_t)__shfl_xor((int)pk[t], 32);
            }
            U4 a1, a2;
            a1.u[0] = hw ? rp[2] : pk[0];
            a1.u[1] = hw ? rp[3] : pk[1];
            a1.u[2] = hw ? pk[2] : rp[0];
            a1.u[3] = hw ? pk[3] : rp[1];
            a2.u[0] = hw ? rp[6] : pk[4];
            a2.u[1] = hw ? rp[7] : pk[5];
            a2.u[2] = hw ? pk[6] : rp[4];
            a2.u[3] = hw ? pk[7] : rp[5];
            // B = [V|1]: n=lane&31 clamped to ones row
            s8v vb1 = *(const s8v*)&vt[ne][kt * 32 + hw * 8];
            s8v vb2 = *(const s8v*)&vt[ne][kt * 32 + 16 + hw * 8];
            O = __builtin_amdgcn_mfma_f32_32x32x16_bf16(a1.v, vb1, O, 0, 0, 0);
            O = __builtin_amdgcn_mfma_f32_32x32x16_bf16(a2.v, vb2, O, 0, 0, 0);
        }
        // O C-layout: col=lane&31=d (0..5; >=6 hold l), row=q
        if (ln < 7) {
            #pragma unroll
            for (int r = 0; r < 16; ++r) {
                int row = (r & 3) + 8 * (r >> 2) + 4 * hw;
                obuf[mt * 32 + row][ln] = O[r];
            }
        }
    }
    __syncthreads();

    // ---- epilogue (per-thread, packed) ----
    v2f o01 = *(const v2f*)&obuf[s][0];
    v2f o23 = *(const v2f*)&obuf[s][2];
    v2f o45 = *(const v2f*)&obuf[s][4];
    float invl = RCPF(obuf[s][6]);
    v2f il = {invl, invl};
    o01 *= il; o23 *= il; o45 *= il;
    float av6[D] = {o01[0], o01[1], o23[0], o23[1], o45[0], o45[1]};

    v2f xvp[3] = {xv01, xv23, xv45};
    v2f x2p[3];
    #pragma unroll
    for (int dp = 0; dp < 3; ++dp) {
        v2f o = ((const v2f*)bo)[dp];
        #pragma unroll
        for (int e = 0; e < D; ++e) {
            v2f we = ((const v2f*)(wo + e * D))[dp];
            v2f ae = {av6[e], av6[e]};
            o = PKFMA(ae, we, o);
        }
        x2p[dp] = o + xvp[dp];
    }
    float x2[D] = {x2p[0][0], x2p[0][1], x2p[1][0], x2p[1][1], x2p[2][0], x2p[2][1]};

    float m2 = 0.f;
    #pragma unroll
    for (int d = 0; d < D; ++d) m2 += x2[d];
    m2 *= (1.0f / D);
    float var2 = 0.f;
    #pragma unroll
    for (int d = 0; d < D; ++d) { float t = x2[d] - m2; var2 += t * t; }
    var2 *= (1.0f / D);
    float rstd2 = rsqrtf(var2 + EPS);
    float h2[D];
    #pragma unroll
    for (int d = 0; d < D; ++d)
        h2[d] = (x2[d] - m2) * rstd2 * ln2_w[d] + ln2_b[d];

    // FFN1 packed + exp2 tanh-GELU (max abs err ~3e-4)
    v2f ap[3];
    #pragma unroll
    for (int jp = 0; jp < 3; ++jp) {
        v2f a = ((const v2f*)b1)[jp];
        #pragma unroll
        for (int d = 0; d < D; ++d) {
            v2f wd = ((const v2f*)(w1 + d * D))[jp];
            v2f hd = {h2[d], h2[d]};
            a = PKFMA(hd, wd, a);
        }
        ap[jp] = a;
    }
    float g[D];
    #pragma unroll
    for (int j = 0; j < D; ++j) {
        float a = ap[j >> 1][j & 1];
        float t  = a * a;
        float in = fmaf(0.044715f * t, a, a);
        float e  = EXP2F(in * -2.3022229f);
        float r  = RCPF(1.0f + e);
        g[j] = a * r;
    }
    #pragma unroll
    for (int dp = 0; dp < 3; ++dp) {
        v2f a = ((const v2f*)b2)[dp];
        #pragma unroll
        for (int e = 0; e < D; ++e) {
            v2f we = ((const v2f*)(w2 + e * D))[dp];
            v2f ge = {g[e], g[e]};
            a = PKFMA(ge, we, a);
        }
        ((v2f*)orow)[dp] = x2p[dp] + a;
    }
}

extern "C" void kernel_launch(void* const* d_in, const int* in_sizes, int n_in,
                              void* d_out, int out_size, void* d_ws, size_t ws_size,
                              hipStream_t stream) {
    const float* x     = (const float*)d_in[0];
    const float* ln1_w = (const float*)d_in[1];
    const float* ln1_b = (const float*)d_in[2];
    const float* wqkv  = (const float*)d_in[3];
    const float* bqkv  = (const float*)d_in[4];
    const float* wo    = (const float*)d_in[5];
    const float* bo    = (const float*)d_in[6];
    const float* ln2_w = (const float*)d_in[7];
    const float* ln2_b = (const float*)d_in[8];
    const float* w1    = (const float*)d_in[9];
    const float* b1    = (const float*)d_in[10];
    const float* w2    = (const float*)d_in[11];
    const float* b2    = (const float*)d_in[12];
    float* out = (float*)d_out;

    const int B = in_sizes[0] / (S * D);
    txblock_kernel<<<B, S, 0, stream>>>(x, ln1_w, ln1_b, wqkv, bqkv, wo, bo,
                                        ln2_w, ln2_b, w1, b1, w2, b2, out);
}

// Round 5
// 116.582 us; speedup vs baseline: 1.3673x; 1.0176x over previous
//
#include <hip/hip_runtime.h>
#include <cmath>

// Tiny transformer block, D=6, S=128, B=8192, fp32.
// R5: 16x16x16 MFMA flash attention — for this shape the C/D layout
// (col=lane&15, row=quad*4+reg) matches the A layout (m=lane&15,
// k=quad*4+i), so exp2(S^T frag) IS the P A-fragment for PV: the R4
// lane^32 bpermute transpose (LDS-pipe bottleneck) vanishes.
//  - 36 causal 16x16 tiles/batch; waves own q-tiles {0,3,4,7}/{1,2,5,6}.
//  - K/Q rows: 6-dword (24B) stride, quads 2/3 redirected to in-row zero
//    pad -> conflict-free b64 fragment reads, LDS ~13.4KB -> 11 blocks/CU.
//  - V^T rows (+ones row at d=6) give the softmax denominator via PV.
// Prologue (packed qkv) and epilogue (wo/LN2/FFN) identical to R4.

typedef float    v2f  __attribute__((ext_vector_type(2)));
typedef float    f4v  __attribute__((ext_vector_type(4)));
typedef short    s4v  __attribute__((ext_vector_type(4)));   // 4 bf16 = 2 VGPRs
typedef uint32_t u2   __attribute__((ext_vector_type(2)));

constexpr int D = 6;
constexpr int S = 128;
#define EPS 1e-5f
#define RSQRT_D 0.4082482904638631f   // 1/sqrt(6)
#define LOG2E   1.4426950408889634f

#define EXP2F(x) __builtin_amdgcn_exp2f(x)
#define RCPF(x)  __builtin_amdgcn_rcpf(x)
#define PKFMA(a, b, c) __builtin_elementwise_fma((a), (b), (c))

union UA { uint32_t u[2]; u2 h; s4v v; };

__device__ __forceinline__ uint32_t pkbf(float hi, float lo) {
    return __builtin_amdgcn_perm(__builtin_bit_cast(uint32_t, hi),
                                 __builtin_bit_cast(uint32_t, lo),
                                 0x07060302u);
}
__device__ __forceinline__ uint16_t bf16t(float x) {
    return (uint16_t)(__builtin_bit_cast(uint32_t, x) >> 16);
}

__device__ __forceinline__ f4v mfma16(s4v a, s4v b, f4v c) {
#if __has_builtin(__builtin_amdgcn_mfma_f32_16x16x16bf16_1k)
    return __builtin_amdgcn_mfma_f32_16x16x16bf16_1k(a, b, c, 0, 0, 0);
#else
    f4v d;
    asm volatile("v_mfma_f32_16x16x16_bf16 %0, %1, %2, %3\n\t"
                 "s_nop 7\n\ts_nop 2"
                 : "=v"(d) : "v"(a), "v"(b), "v"(c));
    return d;
#endif
}

__global__ __launch_bounds__(S, 4) void txblock_kernel(
    const float* __restrict__ x,
    const float* __restrict__ ln1_w, const float* __restrict__ ln1_b,
    const float* __restrict__ wqkv,  const float* __restrict__ bqkv,
    const float* __restrict__ wo,    const float* __restrict__ bo,
    const float* __restrict__ ln2_w, const float* __restrict__ ln2_b,
    const float* __restrict__ w1,    const float* __restrict__ b1,
    const float* __restrict__ w2,    const float* __restrict__ b2,
    float* __restrict__ out)
{
    // K/Q rows: 6 dwords = [f01,f23,f45, 0, 0,0]; dwords 4..5 double as the
    // zero source for quads 2/3 (feats 8..15). 24B stride: gcd(6,32)=2 -> free.
    __shared__ uint32_t qlds[S][6];
    __shared__ uint32_t klds[S][6];
    __shared__ uint16_t vt[8][S + 8]; // V^T d=0..5; row6=1.0; row7=0; 272B stride
    __shared__ float    obuf[S][10];  // o[0..5], l at [6]; 40B stride

    const int b = blockIdx.x;
    const int s = threadIdx.x;
    const float* xrow = x + ((size_t)b * S + s) * D;
    float*      orow = out + ((size_t)b * S + s) * D;

    // ---- load x row ----
    v2f xv01 = ((const v2f*)xrow)[0];
    v2f xv23 = ((const v2f*)xrow)[1];
    v2f xv45 = ((const v2f*)xrow)[2];
    float xv[D] = {xv01[0], xv01[1], xv23[0], xv23[1], xv45[0], xv45[1]};

    // ---- ln1 ----
    float m = 0.f;
    #pragma unroll
    for (int d = 0; d < D; ++d) m += xv[d];
    m *= (1.0f / D);
    float var = 0.f;
    #pragma unroll
    for (int d = 0; d < D; ++d) { float t = xv[d] - m; var += t * t; }
    var *= (1.0f / D);
    float rstd = rsqrtf(var + EPS);
    float h1[D];
    #pragma unroll
    for (int d = 0; d < D; ++d)
        h1[d] = (xv[d] - m) * rstd * ln1_w[d] + ln1_b[d];

    // ---- qkv projection (packed) ----
    v2f aq[3], ak[3], av[3];
    #pragma unroll
    for (int jp = 0; jp < 3; ++jp) {
        aq[jp] = ((const v2f*)bqkv)[jp];
        ak[jp] = ((const v2f*)(bqkv + D))[jp];
        av[jp] = ((const v2f*)(bqkv + 2 * D))[jp];
    }
    #pragma unroll
    for (int d = 0; d < D; ++d) {
        const float* wrow = wqkv + d * 3 * D;
        v2f hd = {h1[d], h1[d]};
        #pragma unroll
        for (int jp = 0; jp < 3; ++jp) {
            aq[jp] = PKFMA(hd, ((const v2f*)wrow)[jp], aq[jp]);
            ak[jp] = PKFMA(hd, ((const v2f*)(wrow + D))[jp], ak[jp]);
            av[jp] = PKFMA(hd, ((const v2f*)(wrow + 2 * D))[jp], av[jp]);
        }
    }
    const v2f qscale = {RSQRT_D * LOG2E, RSQRT_D * LOG2E};

    // ---- stage Q, K, V^T ----
    #pragma unroll
    for (int jp = 0; jp < 3; ++jp) {
        v2f qs = aq[jp] * qscale;
        qlds[s][jp] = pkbf(qs[1], qs[0]);
        klds[s][jp] = pkbf(ak[jp][1], ak[jp][0]);
    }
    qlds[s][3] = 0; qlds[s][4] = 0; qlds[s][5] = 0;
    klds[s][3] = 0; klds[s][4] = 0; klds[s][5] = 0;
    vt[0][s] = bf16t(av[0][0]);
    vt[1][s] = bf16t(av[0][1]);
    vt[2][s] = bf16t(av[1][0]);
    vt[3][s] = bf16t(av[1][1]);
    vt[4][s] = bf16t(av[2][0]);
    vt[5][s] = bf16t(av[2][1]);
    vt[6][s] = 0x3F80;  // bf16 1.0 -> denominator column
    vt[7][s] = 0;       // zero row for clamped n-lanes
    __syncthreads();

    // ---- 16x16 MFMA flash attention ----
    const int wv  = s >> 6;          // wave 0/1
    const int l15 = s & 15;          // m/n index
    const int lq  = (s >> 4) & 3;    // quad within wave
    const int aoff = (lq < 2) ? lq * 8 : 16;   // byte off in K/Q row (quads 2,3 -> zeros)
    const int vne  = (l15 < 7) ? l15 : 7;      // vt row (7 = zeros)

    #pragma unroll
    for (int i = 0; i < 4; ++i) {
        static const int QT0[4] = {0, 3, 4, 7};
        static const int QT1[4] = {1, 2, 5, 6};
        const int qt = wv ? QT1[i] : QT0[i];
        // Q B-frag: B[k=feat][n=q], lane n=l15, k=lq*4+i
        UA qf; qf.h = *(const u2*)((const char*)&qlds[qt * 16 + l15][0] + aoff);
        f4v O = {0.f, 0.f, 0.f, 0.f};
        for (int jt = 0; jt <= qt; ++jt) {
            // K A-frag: A[m=j][k=feat]
            UA kf; kf.h = *(const u2*)((const char*)&klds[jt * 16 + l15][0] + aoff);
            // C[j][q]: lane col=q=l15, rows j=lq*4+r
            f4v c = mfma16(kf.v, qf.v, (f4v){0.f, 0.f, 0.f, 0.f});
            float p0 = EXP2F(c[0]);
            float p1 = EXP2F(c[1]);
            float p2 = EXP2F(c[2]);
            float p3 = EXP2F(c[3]);
            if (jt == qt) {  // diagonal tile: causal mask (wave-uniform branch)
                p0 = (lq * 4 + 0 > l15) ? 0.f : p0;
                p1 = (lq * 4 + 1 > l15) ? 0.f : p1;
                p2 = (lq * 4 + 2 > l15) ? 0.f : p2;
                p3 = (lq * 4 + 3 > l15) ? 0.f : p3;
            }
            // P A-frag == C layout: m=q=l15, k=j=lq*4+i. No cross-lane moves.
            UA pa;
            pa.u[0] = pkbf(p1, p0);
            pa.u[1] = pkbf(p3, p2);
            // V B-frag: B[k=j][n=d], lane n=vne, k=jt*16+lq*4+i
            UA vf; vf.h = *(const u2*)&vt[vne][jt * 16 + lq * 4];
            O = mfma16(pa.v, vf.v, O);
        }
        // O: lane col=d=l15, rows q=lq*4+r
        if (l15 < 7) {
            #pragma unroll
            for (int r = 0; r < 4; ++r)
                obuf[qt * 16 + lq * 4 + r][l15] = O[r];
        }
    }
    __syncthreads();

    // ---- epilogue (per-thread, packed; identical to R4) ----
    v2f o01 = *(const v2f*)&obuf[s][0];
    v2f o23 = *(const v2f*)&obuf[s][2];
    v2f o45 = *(const v2f*)&obuf[s][4];
    float invl = RCPF(obuf[s][6]);
    v2f il = {invl, invl};
    o01 *= il; o23 *= il; o45 *= il;
    float av6[D] = {o01[0], o01[1], o23[0], o23[1], o45[0], o45[1]};

    v2f xvp[3] = {xv01, xv23, xv45};
    v2f x2p[3];
    #pragma unroll
    for (int dp = 0; dp < 3; ++dp) {
        v2f o = ((const v2f*)bo)[dp];
        #pragma unroll
        for (int e = 0; e < D; ++e) {
            v2f we = ((const v2f*)(wo + e * D))[dp];
            v2f ae = {av6[e], av6[e]};
            o = PKFMA(ae, we, o);
        }
        x2p[dp] = o + xvp[dp];
    }
    float x2[D] = {x2p[0][0], x2p[0][1], x2p[1][0], x2p[1][1], x2p[2][0], x2p[2][1]};

    float m2 = 0.f;
    #pragma unroll
    for (int d = 0; d < D; ++d) m2 += x2[d];
    m2 *= (1.0f / D);
    float var2 = 0.f;
    #pragma unroll
    for (int d = 0; d < D; ++d) { float t = x2[d] - m2; var2 += t * t; }
    var2 *= (1.0f / D);
    float rstd2 = rsqrtf(var2 + EPS);
    float h2[D];
    #pragma unroll
    for (int d = 0; d < D; ++d)
        h2[d] = (x2[d] - m2) * rstd2 * ln2_w[d] + ln2_b[d];

    v2f ap[3];
    #pragma unroll
    for (int jp = 0; jp < 3; ++jp) {
        v2f a = ((const v2f*)b1)[jp];
        #pragma unroll
        for (int d = 0; d < D; ++d) {
            v2f wd = ((const v2f*)(w1 + d * D))[jp];
            v2f hd = {h2[d], h2[d]};
            a = PKFMA(hd, wd, a);
        }
        ap[jp] = a;
    }
    float g[D];
    #pragma unroll
    for (int j = 0; j < D; ++j) {
        float a = ap[j >> 1][j & 1];
        float t  = a * a;
        float in = fmaf(0.044715f * t, a, a);
        float e  = EXP2F(in * -2.3022229f);
        float r  = RCPF(1.0f + e);
        g[j] = a * r;
    }
    #pragma unroll
    for (int dp = 0; dp < 3; ++dp) {
        v2f a = ((const v2f*)b2)[dp];
        #pragma unroll
        for (int e = 0; e < D; ++e) {
            v2f we = ((const v2f*)(w2 + e * D))[dp];
            v2f ge = {g[e], g[e]};
            a = PKFMA(ge, we, a);
        }
        ((v2f*)orow)[dp] = x2p[dp] + a;
    }
}

extern "C" void kernel_launch(void* const* d_in, const int* in_sizes, int n_in,
                              void* d_out, int out_size, void* d_ws, size_t ws_size,
                              hipStream_t stream) {
    const float* x     = (const float*)d_in[0];
    const float* ln1_w = (const float*)d_in[1];
    const float* ln1_b = (const float*)d_in[2];
    const float* wqkv  = (const float*)d_in[3];
    const float* bqkv  = (const float*)d_in[4];
    const float* wo    = (const float*)d_in[5];
    const float* bo    = (const float*)d_in[6];
    const float* ln2_w = (const float*)d_in[7];
    const float* ln2_b = (const float*)d_in[8];
    const float* w1    = (const float*)d_in[9];
    const float* b1    = (const float*)d_in[10];
    const float* w2    = (const float*)d_in[11];
    const float* b2    = (const float*)d_in[12];
    float* out = (float*)d_out;

    const int B = in_sizes[0] / (S * D);
    txblock_kernel<<<B, S, 0, stream>>>(x, ln1_w, ln1_b, wqkv, bqkv, wo, bo,
                                        ln2_w, ln2_b, w1, b1, w2, b2, out);
}

// Round 6
// 112.537 us; speedup vs baseline: 1.4165x; 1.0359x over previous
//
#include <hip/hip_runtime.h>
#include <cmath>

// Tiny transformer block, D=6, S=128, B=8192, fp32.
// R6 = R5's verified 16x16x16 MFMA flash core, restructured for latency:
//  - ALL K/V fragments hoisted to registers before the flash loop
//    (8x kf + 8x vf b64 reads = 32 VGPRs) -> zero LDS in the inner loop.
//  - Dual-stream q-tile pairs with equal work: wave0 (0,7),(3,4);
//    wave1 (1,6),(2,5). Two independent O chains interleaved (template
//    compile-time trip counts keep register arrays in registers).
// Prologue (packed qkv) / epilogue (wo, LN2, FFN) identical to R5.

typedef float    v2f  __attribute__((ext_vector_type(2)));
typedef float    f4v  __attribute__((ext_vector_type(4)));
typedef short    s4v  __attribute__((ext_vector_type(4)));   // 4 bf16 = 2 VGPRs
typedef uint32_t u2   __attribute__((ext_vector_type(2)));

constexpr int D = 6;
constexpr int S = 128;
#define EPS 1e-5f
#define RSQRT_D 0.4082482904638631f   // 1/sqrt(6)
#define LOG2E   1.4426950408889634f

#define EXP2F(x) __builtin_amdgcn_exp2f(x)
#define RCPF(x)  __builtin_amdgcn_rcpf(x)
#define PKFMA(a, b, c) __builtin_elementwise_fma((a), (b), (c))

union UA { uint32_t u[2]; u2 h; s4v v; };

__device__ __forceinline__ uint32_t pkbf(float hi, float lo) {
    return __builtin_amdgcn_perm(__builtin_bit_cast(uint32_t, hi),
                                 __builtin_bit_cast(uint32_t, lo),
                                 0x07060302u);
}
__device__ __forceinline__ uint16_t bf16t(float x) {
    return (uint16_t)(__builtin_bit_cast(uint32_t, x) >> 16);
}

__device__ __forceinline__ f4v mfma16(s4v a, s4v b, f4v c) {
#if __has_builtin(__builtin_amdgcn_mfma_f32_16x16x16bf16_1k)
    return __builtin_amdgcn_mfma_f32_16x16x16bf16_1k(a, b, c, 0, 0, 0);
#else
    f4v d;
    asm volatile("v_mfma_f32_16x16x16_bf16 %0, %1, %2, %3\n\t"
                 "s_nop 7\n\ts_nop 2"
                 : "=v"(d) : "v"(a), "v"(b), "v"(c));
    return d;
#endif
}

// One dual-stream pass: q-tiles QA < QB, shared jt loop (A drops out after QA).
template<int QA, int QB>
__device__ __forceinline__ void attn_pair(
    const UA (&kf)[8], const UA (&vf)[8],
    const uint32_t (*qlds)[6], float (*obuf)[10],
    int l15, int lq, int aoff)
{
    UA qfA, qfB;
    qfA.h = *(const u2*)((const char*)&qlds[QA * 16 + l15][0] + aoff);
    qfB.h = *(const u2*)((const char*)&qlds[QB * 16 + l15][0] + aoff);
    const f4v z = {0.f, 0.f, 0.f, 0.f};
    f4v OA = z, OB = z;
    #pragma unroll
    for (int jt = 0; jt <= QB; ++jt) {
        // stream B (always active)
        f4v cB = mfma16(kf[jt].v, qfB.v, z);
        f4v cA;
        if (jt <= QA) cA = mfma16(kf[jt].v, qfA.v, z);
        float pB0 = EXP2F(cB[0]);
        float pB1 = EXP2F(cB[1]);
        float pB2 = EXP2F(cB[2]);
        float pB3 = EXP2F(cB[3]);
        if (jt == QB) {  // diagonal tile of B: causal mask
            pB0 = (lq * 4 + 0 > l15) ? 0.f : pB0;
            pB1 = (lq * 4 + 1 > l15) ? 0.f : pB1;
            pB2 = (lq * 4 + 2 > l15) ? 0.f : pB2;
            pB3 = (lq * 4 + 3 > l15) ? 0.f : pB3;
        }
        UA paB;
        paB.u[0] = pkbf(pB1, pB0);
        paB.u[1] = pkbf(pB3, pB2);
        OB = mfma16(paB.v, vf[jt].v, OB);
        // stream A (compile-time pruned tail)
        if (jt <= QA) {
            float pA0 = EXP2F(cA[0]);
            float pA1 = EXP2F(cA[1]);
            float pA2 = EXP2F(cA[2]);
            float pA3 = EXP2F(cA[3]);
            if (jt == QA) {  // diagonal tile of A
                pA0 = (lq * 4 + 0 > l15) ? 0.f : pA0;
                pA1 = (lq * 4 + 1 > l15) ? 0.f : pA1;
                pA2 = (lq * 4 + 2 > l15) ? 0.f : pA2;
                pA3 = (lq * 4 + 3 > l15) ? 0.f : pA3;
            }
            UA paA;
            paA.u[0] = pkbf(pA1, pA0);
            paA.u[1] = pkbf(pA3, pA2);
            OA = mfma16(paA.v, vf[jt].v, OA);
        }
    }
    // O: lane col=d=l15 (cols 6.. hold the denominator), rows q=lq*4+r
    if (l15 < 7) {
        #pragma unroll
        for (int r = 0; r < 4; ++r) {
            obuf[QA * 16 + lq * 4 + r][l15] = OA[r];
            obuf[QB * 16 + lq * 4 + r][l15] = OB[r];
        }
    }
}

__global__ __launch_bounds__(S, 4) void txblock_kernel(
    const float* __restrict__ x,
    const float* __restrict__ ln1_w, const float* __restrict__ ln1_b,
    const float* __restrict__ wqkv,  const float* __restrict__ bqkv,
    const float* __restrict__ wo,    const float* __restrict__ bo,
    const float* __restrict__ ln2_w, const float* __restrict__ ln2_b,
    const float* __restrict__ w1,    const float* __restrict__ b1,
    const float* __restrict__ w2,    const float* __restrict__ b2,
    float* __restrict__ out)
{
    // K/Q rows: 6 dwords = [f01,f23,f45, 0, 0,0]; quads 2/3 read the zero
    // pad at dwords 4..5. 24B stride: gcd(6,32)=2 -> conflict-free.
    __shared__ uint32_t qlds[S][6];
    __shared__ uint32_t klds[S][6];
    __shared__ uint16_t vt[8][S + 8]; // V^T d=0..5; row6=1.0; row7=0; 272B stride
    __shared__ float    obuf[S][10];  // o[0..5], l at [6]; 40B stride

    const int b = blockIdx.x;
    const int s = threadIdx.x;
    const float* xrow = x + ((size_t)b * S + s) * D;
    float*      orow = out + ((size_t)b * S + s) * D;

    // ---- load x row ----
    v2f xv01 = ((const v2f*)xrow)[0];
    v2f xv23 = ((const v2f*)xrow)[1];
    v2f xv45 = ((const v2f*)xrow)[2];
    float xv[D] = {xv01[0], xv01[1], xv23[0], xv23[1], xv45[0], xv45[1]};

    // ---- ln1 ----
    float m = 0.f;
    #pragma unroll
    for (int d = 0; d < D; ++d) m += xv[d];
    m *= (1.0f / D);
    float var = 0.f;
    #pragma unroll
    for (int d = 0; d < D; ++d) { float t = xv[d] - m; var += t * t; }
    var *= (1.0f / D);
    float rstd = rsqrtf(var + EPS);
    float h1[D];
    #pragma unroll
    for (int d = 0; d < D; ++d)
        h1[d] = (xv[d] - m) * rstd * ln1_w[d] + ln1_b[d];

    // ---- qkv projection (packed) ----
    v2f aq[3], ak[3], av[3];
    #pragma unroll
    for (int jp = 0; jp < 3; ++jp) {
        aq[jp] = ((const v2f*)bqkv)[jp];
        ak[jp] = ((const v2f*)(bqkv + D))[jp];
        av[jp] = ((const v2f*)(bqkv + 2 * D))[jp];
    }
    #pragma unroll
    for (int d = 0; d < D; ++d) {
        const float* wrow = wqkv + d * 3 * D;
        v2f hd = {h1[d], h1[d]};
        #pragma unroll
        for (int jp = 0; jp < 3; ++jp) {
            aq[jp] = PKFMA(hd, ((const v2f*)wrow)[jp], aq[jp]);
            ak[jp] = PKFMA(hd, ((const v2f*)(wrow + D))[jp], ak[jp]);
            av[jp] = PKFMA(hd, ((const v2f*)(wrow + 2 * D))[jp], av[jp]);
        }
    }
    const v2f qscale = {RSQRT_D * LOG2E, RSQRT_D * LOG2E};

    // ---- stage Q, K, V^T ----
    #pragma unroll
    for (int jp = 0; jp < 3; ++jp) {
        v2f qs = aq[jp] * qscale;
        qlds[s][jp] = pkbf(qs[1], qs[0]);
        klds[s][jp] = pkbf(ak[jp][1], ak[jp][0]);
    }
    qlds[s][3] = 0; qlds[s][4] = 0; qlds[s][5] = 0;
    klds[s][3] = 0; klds[s][4] = 0; klds[s][5] = 0;
    vt[0][s] = bf16t(av[0][0]);
    vt[1][s] = bf16t(av[0][1]);
    vt[2][s] = bf16t(av[1][0]);
    vt[3][s] = bf16t(av[1][1]);
    vt[4][s] = bf16t(av[2][0]);
    vt[5][s] = bf16t(av[2][1]);
    vt[6][s] = 0x3F80;  // bf16 1.0 -> denominator column
    vt[7][s] = 0;       // zero row for clamped n-lanes
    __syncthreads();

    // ---- 16x16 MFMA flash attention, register-resident K/V ----
    const int wv  = s >> 6;
    const int l15 = s & 15;
    const int lq  = (s >> 4) & 3;
    const int aoff = (lq < 2) ? lq * 8 : 16;   // quads 2/3 -> zero pad
    const int vne  = (l15 < 7) ? l15 : 7;      // 0..5=V rows, 6=ones, 7=zeros

    UA kf[8], vf[8];
    #pragma unroll
    for (int jt = 0; jt < 8; ++jt) {
        kf[jt].h = *(const u2*)((const char*)&klds[jt * 16 + l15][0] + aoff);
        vf[jt].h = *(const u2*)&vt[vne][jt * 16 + lq * 4];
    }

    if (wv == 0) {
        attn_pair<0, 7>(kf, vf, qlds, obuf, l15, lq, aoff);
        attn_pair<3, 4>(kf, vf, qlds, obuf, l15, lq, aoff);
    } else {
        attn_pair<1, 6>(kf, vf, qlds, obuf, l15, lq, aoff);
        attn_pair<2, 5>(kf, vf, qlds, obuf, l15, lq, aoff);
    }
    __syncthreads();

    // ---- epilogue (per-thread, packed; identical to R5) ----
    v2f o01 = *(const v2f*)&obuf[s][0];
    v2f o23 = *(const v2f*)&obuf[s][2];
    v2f o45 = *(const v2f*)&obuf[s][4];
    float invl = RCPF(obuf[s][6]);
    v2f il = {invl, invl};
    o01 *= il; o23 *= il; o45 *= il;
    float av6[D] = {o01[0], o01[1], o23[0], o23[1], o45[0], o45[1]};

    v2f xvp[3] = {xv01, xv23, xv45};
    v2f x2p[3];
    #pragma unroll
    for (int dp = 0; dp < 3; ++dp) {
        v2f o = ((const v2f*)bo)[dp];
        #pragma unroll
        for (int e = 0; e < D; ++e) {
            v2f we = ((const v2f*)(wo + e * D))[dp];
            v2f ae = {av6[e], av6[e]};
            o = PKFMA(ae, we, o);
        }
        x2p[dp] = o + xvp[dp];
    }
    float x2[D] = {x2p[0][0], x2p[0][1], x2p[1][0], x2p[1][1], x2p[2][0], x2p[2][1]};

    float m2 = 0.f;
    #pragma unroll
    for (int d = 0; d < D; ++d) m2 += x2[d];
    m2 *= (1.0f / D);
    float var2 = 0.f;
    #pragma unroll
    for (int d = 0; d < D; ++d) { float t = x2[d] - m2; var2 += t * t; }
    var2 *= (1.0f / D);
    float rstd2 = rsqrtf(var2 + EPS);
    float h2[D];
    #pragma unroll
    for (int d = 0; d < D; ++d)
        h2[d] = (x2[d] - m2) * rstd2 * ln2_w[d] + ln2_b[d];

    v2f ap[3];
    #pragma unroll
    for (int jp = 0; jp < 3; ++jp) {
        v2f a = ((const v2f*)b1)[jp];
        #pragma unroll
        for (int d = 0; d < D; ++d) {
            v2f wd = ((const v2f*)(w1 + d * D))[jp];
            v2f hd = {h2[d], h2[d]};
            a = PKFMA(hd, wd, a);
        }
        ap[jp] = a;
    }
    float g[D];
    #pragma unroll
    for (int j = 0; j < D; ++j) {
        float a = ap[j >> 1][j & 1];
        float t  = a * a;
        float in = fmaf(0.044715f * t, a, a);
        float e  = EXP2F(in * -2.3022229f);
        float r  = RCPF(1.0f + e);
        g[j] = a * r;
    }
    #pragma unroll
    for (int dp = 0; dp < 3; ++dp) {
        v2f a = ((const v2f*)b2)[dp];
        #pragma unroll
        for (int e = 0; e < D; ++e) {
            v2f we = ((const v2f*)(w2 + e * D))[dp];
            v2f ge = {g[e], g[e]};
            a = PKFMA(ge, we, a);
        }
        ((v2f*)orow)[dp] = x2p[dp] + a;
    }
}

extern "C" void kernel_launch(void* const* d_in, const int* in_sizes, int n_in,
                              void* d_out, int out_size, void* d_ws, size_t ws_size,
                              hipStream_t stream) {
    const float* x     = (const float*)d_in[0];
    const float* ln1_w = (const float*)d_in[1];
    const float* ln1_b = (const float*)d_in[2];
    const float* wqkv  = (const float*)d_in[3];
    const float* bqkv  = (const float*)d_in[4];
    const float* wo    = (const float*)d_in[5];
    const float* bo    = (const float*)d_in[6];
    const float* ln2_w = (const float*)d_in[7];
    const float* ln2_b = (const float*)d_in[8];
    const float* w1    = (const float*)d_in[9];
    const float* b1    = (const float*)d_in[10];
    const float* w2    = (const float*)d_in[11];
    const float* b2    = (const float*)d_in[12];
    float* out = (float*)d_out;

    const int B = in_sizes[0] / (S * D);
    txblock_kernel<<<B, S, 0, stream>>>(x, ln1_w, ln1_b, wqkv, bqkv, wo, bo,
                                        ln2_w, ln2_b, w1, b1, w2, b2, out);
}